// Round 1
// baseline (153.814 us; speedup 1.0000x reference)
//
#include <hip/hip_runtime.h>

#define N     384
#define BSZ   192
#define NM1   383
#define D     1024
#define DELTA 0.1f
#define JB    12   // j-tiles in k_main
#define JT    32   // j per tile (last tile has 31)

__device__ __forceinline__ const float* feat_row(const float* feats, int i) {
    // features laid out [192][2][1024]; logical row i of the [384,1024] concat
    int b = (i < BSZ) ? i : (i - BSZ);
    int s = (i < BSZ) ? 0 : 1;
    return feats + (size_t)(b * 2 + s) * D;
}

// z[i][k] = || feats_i - feats_col(i,k) ||_2, off-diagonal layout (col = k + (k>=i))
__global__ __launch_bounds__(256) void k_z(const float* __restrict__ feats,
                                           float* __restrict__ z) {
    const int i    = blockIdx.x;
    const int lane = threadIdx.x & 63;
    const int wave = threadIdx.x >> 6;

    const float* fi = feat_row(feats, i);
    float fr[16];
#pragma unroll
    for (int s = 0; s < 16; ++s) fr[s] = fi[lane + 64 * s];

    for (int j = wave; j < N; j += 4) {
        const float* fj = feat_row(feats, j);
        float p = 0.f;
#pragma unroll
        for (int s = 0; s < 16; ++s) {
            float t = fr[s] - fj[lane + 64 * s];
            p = fmaf(t, t, p);
        }
#pragma unroll
        for (int off = 32; off; off >>= 1) p += __shfl_xor(p, off);
        if (lane == 0 && j != i) {
            int k = (j < i) ? j : j - 1;
            z[i * NM1 + k] = sqrtf(p);
        }
    }
}

// y_abs (uint8) and dense-rank (float) per row. Labels in [0,50) so |diff| < 64.
__global__ __launch_bounds__(64) void k_rank(const int* __restrict__ labels,
                                             unsigned char* __restrict__ yab,
                                             float* __restrict__ rkf) {
    const int i   = blockIdx.x;
    const int tid = threadIdx.x;
    __shared__ int   hist[64];
    __shared__ float rankOf[64];
    hist[tid] = 0;
    __syncthreads();

    const int li = labels[(i < BSZ) ? i : (i - BSZ)];
    for (int k = tid; k < NM1; k += 64) {
        int col = k + (k >= i ? 1 : 0);
        int lc  = labels[(col < BSZ) ? col : (col - BSZ)];
        int ya  = abs(li - lc);
        yab[i * NM1 + k] = (unsigned char)ya;
        hist[ya] = 1;   // benign race: all writers store 1
    }
    __syncthreads();
    if (tid == 0) {
        int c = 0;
        for (int v = 0; v < 64; ++v) { rankOf[v] = (float)c; c += hist[v]; }
    }
    __syncthreads();
    for (int k = tid; k < NM1; k += 64)
        rkf[i * NM1 + k] = rankOf[yab[i * NM1 + k]];
}

// Main 56.3M-pair sweep. One double atomicAdd per block (pos+neg share denominator).
__global__ __launch_bounds__(128) void k_main(const float* __restrict__ z,
                                              const unsigned char* __restrict__ yab,
                                              const float* __restrict__ rkf,
                                              double* __restrict__ acc) {
    const int i   = blockIdx.x / JB;
    const int jt  = blockIdx.x % JB;
    const int tid = threadIdx.x;

    __shared__ float zs[NM1];
    __shared__ float rs[NM1];
    __shared__ int   ys[NM1];
    for (int k = tid; k < NM1; k += 128) {
        zs[k] = z[i * NM1 + k];
        rs[k] = rkf[i * NM1 + k];
        ys[k] = (int)yab[i * NM1 + k];
    }
    __syncthreads();

    const int j0 = jt * JT;
    const int j1 = (j0 + JT < NM1) ? (j0 + JT) : NM1;

    float sum = 0.f;
    for (int j = j0; j < j1; ++j) {
        const float zj = zs[j];
        const float rj = rs[j];
        const int   yj = ys[j];
        for (int k = tid; k < NM1; k += 128) {
            float a = fabsf(zs[k] - zj);
            if (ys[k] == yj) {
                // a * sigmoid(a - DELTA); sigmoid(x) = 1/(1+exp(-x))
                float sg = 1.f / (1.f + __expf(DELTA - a));
                sum += a * sg;
            } else {
                float m = fabsf(rs[k] - rj) * DELTA;
                float t = a - m;
                sum = fmaf(t, t, sum);
            }
        }
    }

#pragma unroll
    for (int off = 32; off; off >>= 1) sum += __shfl_xor(sum, off);
    __shared__ float part[2];
    if ((tid & 63) == 0) part[tid >> 6] = sum;
    __syncthreads();
    if (tid == 0) atomicAdd(acc, (double)(part[0] + part[1]));
}

__global__ void k_fin(const double* __restrict__ acc, float* __restrict__ out) {
    const double M = (double)N * (double)NM1 * (double)NM1;
    out[0] = (float)(acc[0] / M);
}

extern "C" void kernel_launch(void* const* d_in, const int* in_sizes, int n_in,
                              void* d_out, int out_size, void* d_ws, size_t ws_size,
                              hipStream_t stream) {
    const float* feats  = (const float*)d_in[0];
    const int*   labels = (const int*)d_in[1];
    float*       out    = (float*)d_out;

    char* ws = (char*)d_ws;
    double*        acc = (double*)ws;                                    // 16 B
    float*         z   = (float*)(ws + 16);                              // 384*383*4
    float*         rkf = (float*)(ws + 16 + (size_t)N * NM1 * 4);        // 384*383*4
    unsigned char* yab = (unsigned char*)(ws + 16 + (size_t)2 * N * NM1 * 4);

    hipMemsetAsync(acc, 0, sizeof(double), stream);
    k_z   <<<N, 256, 0, stream>>>(feats, z);
    k_rank<<<N, 64, 0, stream>>>(labels, yab, rkf);
    k_main<<<N * JB, 128, 0, stream>>>(z, yab, rkf, acc);
    k_fin <<<1, 1, 0, stream>>>(acc, out);
}

// Round 2
// 105.393 us; speedup vs baseline: 1.4594x; 1.4594x over previous
//
#include <hip/hip_runtime.h>

#define N     384
#define BSZ   192
#define NM1   383
#define D     1024
#define DELTA 0.1f
#define JB    12   // j-tiles in k_main
#define JT    32   // j per tile (last tile has 31)
#define ZJB   6    // j-tiles in k_z
#define ZJT   64   // j per tile in k_z

__device__ __forceinline__ const float* feat_row(const float* feats, int i) {
    // features laid out [192][2][1024]; logical row i of the [384,1024] concat
    int b = (i < BSZ) ? i : (i - BSZ);
    int s = (i < BSZ) ? 0 : 1;
    return feats + (size_t)(b * 2 + s) * D;
}

// z[i][k] = || feats_i - feats_col(i,k) ||_2, off-diagonal layout (col = k + (k>=i))
// Grid (N, ZJB) x 256. Each wave handles 16 j's, unrolled 2-wide for ILP.
// float4 loads: SSD is permutation-invariant over positions, so any consistent
// lane->position mapping works.
__global__ __launch_bounds__(256) void k_z(const float* __restrict__ feats,
                                           float* __restrict__ z) {
    const int i    = blockIdx.x;
    const int jt   = blockIdx.y;
    const int lane = threadIdx.x & 63;
    const int wave = threadIdx.x >> 6;

    const float4* fi4 = (const float4*)feat_row(feats, i);
    float4 fr[4];
#pragma unroll
    for (int c = 0; c < 4; ++c) fr[c] = fi4[lane + 64 * c];

    const int j0 = jt * ZJT;
#pragma unroll 2
    for (int t = 0; t < 16; t += 2) {
        const int jA = j0 + wave + 4 * t;
        const int jB = j0 + wave + 4 * (t + 1);
        const float4* fA = (const float4*)feat_row(feats, jA);
        const float4* fB = (const float4*)feat_row(feats, jB);
        float pA = 0.f, pB = 0.f;
#pragma unroll
        for (int c = 0; c < 4; ++c) {
            float4 a = fA[lane + 64 * c];
            float4 b = fB[lane + 64 * c];
            float t0;
            t0 = fr[c].x - a.x; pA = fmaf(t0, t0, pA);
            t0 = fr[c].y - a.y; pA = fmaf(t0, t0, pA);
            t0 = fr[c].z - a.z; pA = fmaf(t0, t0, pA);
            t0 = fr[c].w - a.w; pA = fmaf(t0, t0, pA);
            t0 = fr[c].x - b.x; pB = fmaf(t0, t0, pB);
            t0 = fr[c].y - b.y; pB = fmaf(t0, t0, pB);
            t0 = fr[c].z - b.z; pB = fmaf(t0, t0, pB);
            t0 = fr[c].w - b.w; pB = fmaf(t0, t0, pB);
        }
#pragma unroll
        for (int off = 32; off; off >>= 1) {
            pA += __shfl_xor(pA, off);
            pB += __shfl_xor(pB, off);
        }
        if (lane == 0) {
            if (jA != i) z[i * NM1 + (jA < i ? jA : jA - 1)] = sqrtf(pA);
            if (jB != i) z[i * NM1 + (jB < i ? jB : jB - 1)] = sqrtf(pB);
        }
    }
}

// y_abs (uint8) and dense-rank * DELTA (float) per row. Labels in [0,50).
__global__ __launch_bounds__(64) void k_rank(const int* __restrict__ labels,
                                             unsigned char* __restrict__ yab,
                                             float* __restrict__ rkf) {
    const int i   = blockIdx.x;
    const int tid = threadIdx.x;
    __shared__ int   hist[64];
    __shared__ float rankOf[64];
    hist[tid] = 0;
    __syncthreads();

    const int li = labels[(i < BSZ) ? i : (i - BSZ)];
    for (int k = tid; k < NM1; k += 64) {
        int col = k + (k >= i ? 1 : 0);
        int lc  = labels[(col < BSZ) ? col : (col - BSZ)];
        int ya  = abs(li - lc);
        yab[i * NM1 + k] = (unsigned char)ya;
        hist[ya] = 1;   // benign race: all writers store 1
    }
    __syncthreads();
    if (tid == 0) {
        int c = 0;
        for (int v = 0; v < 64; ++v) { rankOf[v] = (float)c * DELTA; c += hist[v]; }
    }
    __syncthreads();
    for (int k = tid; k < NM1; k += 64)
        rkf[i * NM1 + k] = rankOf[yab[i * NM1 + k]];
}

// Branchless per-pair value. rk/rj are rank*DELTA already.
__device__ __forceinline__ float pairv(float zk, float rk, int yk,
                                       float zj, float rj, int yj) {
    float a   = fabsf(zk - zj);
    float m   = fabsf(rk - rj);
    float t   = a - m;
    float neg = t * t;
    float e   = __expf(DELTA - a);
    float pos = a * __builtin_amdgcn_rcpf(1.f + e);
    return (yk == yj) ? pos : neg;
}

// Main 56.3M-pair sweep. Registers hold each thread's 3 k-values; inner j-loop
// reads 3 broadcast LDS values and runs 3 independent chains.
__global__ __launch_bounds__(128) void k_main(const float* __restrict__ z,
                                              const unsigned char* __restrict__ yab,
                                              const float* __restrict__ rkf,
                                              double* __restrict__ acc) {
    const int i   = blockIdx.x;
    const int jt  = blockIdx.y;
    const int tid = threadIdx.x;

    __shared__ float zs[NM1];
    __shared__ float rs[NM1];
    __shared__ int   ys[NM1];
    for (int k = tid; k < NM1; k += 128) {
        zs[k] = z[i * NM1 + k];
        rs[k] = rkf[i * NM1 + k];
        ys[k] = (int)yab[i * NM1 + k];
    }
    __syncthreads();

    const int k0 = tid, k1 = tid + 128, k2 = tid + 256;
    const float zk0 = zs[k0], rk0 = rs[k0]; const int yk0 = ys[k0];
    const float zk1 = zs[k1], rk1 = rs[k1]; const int yk1 = ys[k1];
    const bool  v2  = (k2 < NM1);
    const float zk2 = v2 ? zs[k2] : 0.f;
    const float rk2 = v2 ? rs[k2] : 0.f;
    const int   yk2 = v2 ? ys[k2] : -1;

    const int j0 = jt * JT;
    const int j1 = (j0 + JT < NM1) ? (j0 + JT) : NM1;

    float sum0 = 0.f, sum1 = 0.f, sum2 = 0.f;
    for (int j = j0; j < j1; ++j) {
        const float zj = zs[j];
        const float rj = rs[j];
        const int   yj = ys[j];
        sum0 += pairv(zk0, rk0, yk0, zj, rj, yj);
        sum1 += pairv(zk1, rk1, yk1, zj, rj, yj);
        float c2 = pairv(zk2, rk2, yk2, zj, rj, yj);
        sum2 += v2 ? c2 : 0.f;
    }

    float sum = sum0 + sum1 + sum2;
#pragma unroll
    for (int off = 32; off; off >>= 1) sum += __shfl_xor(sum, off);
    __shared__ float part[2];
    if ((tid & 63) == 0) part[tid >> 6] = sum;
    __syncthreads();
    if (tid == 0) atomicAdd(acc, (double)(part[0] + part[1]));
}

__global__ void k_fin(const double* __restrict__ acc, float* __restrict__ out) {
    const double M = (double)N * (double)NM1 * (double)NM1;
    out[0] = (float)(acc[0] / M);
}

extern "C" void kernel_launch(void* const* d_in, const int* in_sizes, int n_in,
                              void* d_out, int out_size, void* d_ws, size_t ws_size,
                              hipStream_t stream) {
    const float* feats  = (const float*)d_in[0];
    const int*   labels = (const int*)d_in[1];
    float*       out    = (float*)d_out;

    char* ws = (char*)d_ws;
    double*        acc = (double*)ws;                                    // 16 B
    float*         z   = (float*)(ws + 16);                              // 384*383*4
    float*         rkf = (float*)(ws + 16 + (size_t)N * NM1 * 4);        // 384*383*4
    unsigned char* yab = (unsigned char*)(ws + 16 + (size_t)2 * N * NM1 * 4);

    hipMemsetAsync(acc, 0, sizeof(double), stream);
    k_z   <<<dim3(N, ZJB), 256, 0, stream>>>(feats, z);
    k_rank<<<N, 64, 0, stream>>>(labels, yab, rkf);
    k_main<<<dim3(N, JB), 128, 0, stream>>>(z, yab, rkf, acc);
    k_fin <<<1, 1, 0, stream>>>(acc, out);
}

// Round 3
// 96.996 us; speedup vs baseline: 1.5858x; 1.0866x over previous
//
#include <hip/hip_runtime.h>

#define N     384
#define BSZ   192
#define NM1   383
#define D     1024
#define DELTA 0.1f
#define JB    12   // j-tiles in k_main
#define JT    32   // j per tile
#define TI    6    // i-rows per k_z block
#define TJZ   32   // j per k_z block

typedef float v2f __attribute__((ext_vector_type(2)));

__device__ __forceinline__ const float* feat_row(const float* feats, int i) {
    // features laid out [192][2][1024]; logical row i of the [384,1024] concat
    int b = (i < BSZ) ? i : (i - BSZ);
    int s = (i < BSZ) ? 0 : 1;
    return feats + (size_t)(b * 2 + s) * D;
}

// |f_i|^2 per row.
__global__ __launch_bounds__(64) void k_sq(const float* __restrict__ feats,
                                           float* __restrict__ sq) {
    const int i = blockIdx.x, lane = threadIdx.x;
    const float4* f4 = (const float4*)feat_row(feats, i);
    float p = 0.f;
#pragma unroll
    for (int c = 0; c < 4; ++c) {
        float4 v = f4[lane + 64 * c];
        p = fmaf(v.x, v.x, p); p = fmaf(v.y, v.y, p);
        p = fmaf(v.z, v.z, p); p = fmaf(v.w, v.w, p);
    }
#pragma unroll
    for (int off = 32; off; off >>= 1) p += __shfl_xor(p, off);
    if (lane == 0) sq[i] = p;
}

// z[i][k] = sqrt(max(sq_i + sq_j - 2*dot, 0))  (Gram form, same as reference).
// Block: TI i-rows (register-resident lane slices) x TJZ j's; 4 waves, 8 j/wave.
__global__ __launch_bounds__(256) void k_z(const float* __restrict__ feats,
                                           const float* __restrict__ sq,
                                           float* __restrict__ z) {
    const int i0   = blockIdx.x * TI;
    const int jt   = blockIdx.y;
    const int lane = threadIdx.x & 63;
    const int wave = threadIdx.x >> 6;

    __shared__ float sqs[N];
    for (int t = threadIdx.x; t < N; t += 256) sqs[t] = sq[t];

    v2f fr[TI][8];
#pragma unroll
    for (int a = 0; a < TI; ++a) {
        const float4* fi4 = (const float4*)feat_row(feats, i0 + a);
#pragma unroll
        for (int c = 0; c < 4; ++c) {
            float4 v = fi4[lane + 64 * c];
            fr[a][2*c]   = (v2f){v.x, v.y};
            fr[a][2*c+1] = (v2f){v.z, v.w};
        }
    }
    __syncthreads();
    float sqi[TI];
#pragma unroll
    for (int a = 0; a < TI; ++a) sqi[a] = sqs[i0 + a];

#pragma unroll 2
    for (int t = 0; t < 8; ++t) {
        const int j = jt * TJZ + wave * 8 + t;
        const float4* fj4 = (const float4*)feat_row(feats, j);
        v2f bb[8];
#pragma unroll
        for (int c = 0; c < 4; ++c) {
            float4 v = fj4[lane + 64 * c];
            bb[2*c]   = (v2f){v.x, v.y};
            bb[2*c+1] = (v2f){v.z, v.w};
        }
        float p[TI];
#pragma unroll
        for (int a = 0; a < TI; ++a) {
            v2f acc = (v2f){0.f, 0.f};
#pragma unroll
            for (int c = 0; c < 8; ++c) acc += fr[a][c] * bb[c];
            p[a] = acc.x + acc.y;
        }
#pragma unroll
        for (int off = 32; off; off >>= 1) {
#pragma unroll
            for (int a = 0; a < TI; ++a) p[a] += __shfl_xor(p[a], off);
        }
        if (lane == 0) {
            const float sqj = sqs[j];
#pragma unroll
            for (int a = 0; a < TI; ++a) {
                const int i = i0 + a;
                if (j != i) {
                    float s = fmaxf(sqi[a] + sqj - 2.f * p[a], 0.f);
                    z[i * NM1 + (j < i ? j : j - 1)] = sqrtf(s);
                }
            }
        }
    }
}

// Counting-sort each row by y_abs value (in place via LDS buffer); emit packed
// group info per sorted element: lo(9b) | hi(9b)<<9 | dense_rank(6b)<<18.
__global__ __launch_bounds__(64) void k_prep(const int* __restrict__ labels,
                                             float* __restrict__ z,
                                             unsigned* __restrict__ gr) {
    const int i = blockIdx.x, tid = threadIdx.x;
    __shared__ float zbuf[NM1];
    __shared__ unsigned char yrow[NM1];
    __shared__ int cnt[64], startv[64], cur[64], rnk[64];
    cnt[tid] = 0;
    for (int k = tid; k < NM1; k += 64) zbuf[k] = z[i * NM1 + k];
    __syncthreads();
    const int li = labels[(i < BSZ) ? i : (i - BSZ)];
    for (int k = tid; k < NM1; k += 64) {
        int col = k + (k >= i ? 1 : 0);
        int ya  = abs(li - labels[(col < BSZ) ? col : (col - BSZ)]);
        yrow[k] = (unsigned char)ya;
        atomicAdd(&cnt[ya], 1);
    }
    __syncthreads();
    if (tid == 0) {
        int c = 0, r = 0;
        for (int v = 0; v < 64; ++v) {
            startv[v] = c;
            rnk[v] = r;
            if (cnt[v] > 0) ++r;
            c += cnt[v];
        }
    }
    __syncthreads();
    cur[tid] = startv[tid];
    __syncthreads();
    for (int k = tid; k < NM1; k += 64) {
        int ya  = yrow[k];
        int pos = atomicAdd(&cur[ya], 1);
        z[i * NM1 + pos] = zbuf[k];
        gr[i * NM1 + pos] = (unsigned)startv[ya]
                          | ((unsigned)(startv[ya] + cnt[ya]) << 9)
                          | ((unsigned)rnk[ya] << 18);
    }
}

// Main sweep: sum over ALL pairs of (|zk-zj| - |rk-rj|)^2 (4 VALU/pair, no
// trans, no y), plus sparse correction a*sigmoid(a-DELTA) - a^2 over same-y
// pairs (contiguous [lo,hi) ranges thanks to the sort).
__global__ __launch_bounds__(128) void k_main(const float* __restrict__ z,
                                              const unsigned* __restrict__ gr,
                                              double* __restrict__ acc) {
    const int i = blockIdx.x, jt = blockIdx.y, tid = threadIdx.x;
    __shared__ float2 zr[N];      // sorted (z, rank*DELTA); slot 383 zero-init
    __shared__ unsigned grs[N];
    for (int k = tid; k < NM1; k += 128) {
        unsigned g = gr[i * NM1 + k];
        zr[k]  = make_float2(z[i * NM1 + k], (float)(g >> 18) * DELTA);
        grs[k] = g;
    }
    if (tid == 0) { zr[NM1] = make_float2(0.f, 0.f); grs[NM1] = 0; }
    __syncthreads();

    const int  k0 = tid, k1 = tid + 128, k2 = tid + 256;
    const bool v2 = (k2 < NM1);
    const float zk0 = zr[k0].x, rk0 = zr[k0].y;
    const float zk1 = zr[k1].x, rk1 = zr[k1].y;
    const float zk2 = zr[v2 ? k2 : 0].x, rk2 = zr[v2 ? k2 : 0].y; // dup discarded below

    const int j0 = jt * JT;
    const int j1 = (j0 + JT < NM1) ? j0 + JT : NM1;

    float s0 = 0.f, s1 = 0.f, s2 = 0.f;
#define PAIRQ(q) do { \
        float t0 = fabsf(zk0 - (q).x) - fabsf(rk0 - (q).y); s0 = fmaf(t0, t0, s0); \
        float t1 = fabsf(zk1 - (q).x) - fabsf(rk1 - (q).y); s1 = fmaf(t1, t1, s1); \
        float t2 = fabsf(zk2 - (q).x) - fabsf(rk2 - (q).y); s2 = fmaf(t2, t2, s2); \
    } while (0)
    int j = j0;
    for (; j + 4 <= j1; j += 4) {
        float2 q0 = zr[j], q1 = zr[j+1], q2 = zr[j+2], q3 = zr[j+3];
        PAIRQ(q0); PAIRQ(q1); PAIRQ(q2); PAIRQ(q3);
    }
    for (; j < j1; ++j) { float2 q = zr[j]; PAIRQ(q); }
#undef PAIRQ

    // correction over same-y pairs: 4 threads per j, strided over [lo,hi)
    float cs = 0.f;
    const int jj = j0 + (tid >> 2);
    if (jj < j1) {
        const float    zj = zr[jj].x;
        const unsigned g  = grs[jj];
        const int lo = g & 0x1FF;
        const int hi = (g >> 9) & 0x1FF;
        for (int k = lo + (tid & 3); k < hi; k += 4) {
            float a  = fabsf(zr[k].x - zj);
            float e  = __expf(DELTA - a);
            float sg = __builtin_amdgcn_rcpf(1.f + e);
            cs += a * sg - a * a;
        }
    }

    float sum = s0 + s1 + (v2 ? s2 : 0.f) + cs;
#pragma unroll
    for (int off = 32; off; off >>= 1) sum += __shfl_xor(sum, off);
    __shared__ float part[2];
    if ((tid & 63) == 0) part[tid >> 6] = sum;
    __syncthreads();
    if (tid == 0) atomicAdd(acc, (double)(part[0] + part[1]));
}

__global__ void k_fin(const double* __restrict__ acc, float* __restrict__ out) {
    const double M = (double)N * (double)NM1 * (double)NM1;
    out[0] = (float)(acc[0] / M);
}

extern "C" void kernel_launch(void* const* d_in, const int* in_sizes, int n_in,
                              void* d_out, int out_size, void* d_ws, size_t ws_size,
                              hipStream_t stream) {
    const float* feats  = (const float*)d_in[0];
    const int*   labels = (const int*)d_in[1];
    float*       out    = (float*)d_out;

    char* ws = (char*)d_ws;
    double*   acc = (double*)ws;                                  // 16 B
    float*    z   = (float*)(ws + 16);                            // 384*383*4
    unsigned* gr  = (unsigned*)(ws + 16 + (size_t)N * NM1 * 4);   // 384*383*4
    float*    sq  = (float*)(ws + 16 + (size_t)2 * N * NM1 * 4);  // 384*4

    hipMemsetAsync(acc, 0, sizeof(double), stream);
    k_sq  <<<N, 64, 0, stream>>>(feats, sq);
    k_z   <<<dim3(N / TI, (N + TJZ - 1) / TJZ), 256, 0, stream>>>(feats, sq, z);
    k_prep<<<N, 64, 0, stream>>>(labels, z, gr);
    k_main<<<dim3(N, JB), 128, 0, stream>>>(z, gr, acc);
    k_fin <<<1, 1, 0, stream>>>(acc, out);
}

// Round 4
// 45.502 us; speedup vs baseline: 3.3804x; 2.1317x over previous
//
#include <hip/hip_runtime.h>

#define N     384
#define BSZ   192
#define NM1   383
#define D     1024
#define DELTA 0.1f
#define JB    6    // j-tiles in k_main
#define JT    64   // j per tile

typedef __attribute__((ext_vector_type(8))) short bf16x8;
typedef __attribute__((ext_vector_type(4))) float f32x4;

__device__ __forceinline__ const float* feat_row(const float* feats, int i) {
    // features laid out [192][2][1024]; logical row i of the [384,1024] concat
    int b = (i < BSZ) ? i : (i - BSZ);
    int s = (i < BSZ) ? 0 : 1;
    return feats + (size_t)(b * 2 + s) * D;
}

__device__ __forceinline__ unsigned short f2bf(float x) {  // RNE f32->bf16
    unsigned u = __builtin_bit_cast(unsigned, x);
    u = (u + 0x7FFFu + ((u >> 16) & 1u)) >> 16;
    return (unsigned short)u;
}
__device__ __forceinline__ float bf2f(unsigned short h) {
    unsigned u = ((unsigned)h) << 16;
    return __builtin_bit_cast(float, u);
}

// f32 -> (H, L) bf16 split + |f_i|^2. H+L carries ~16 mantissa bits.
__global__ __launch_bounds__(64) void k_cvt(const float* __restrict__ feats,
                                            unsigned short* __restrict__ Hb,
                                            unsigned short* __restrict__ Lb,
                                            float* __restrict__ sq) {
    const int i = blockIdx.x, lane = threadIdx.x;
    const float4* f4 = (const float4*)feat_row(feats, i);
    float p = 0.f;
#pragma unroll
    for (int c = 0; c < 4; ++c) {
        float4 v = f4[lane + 64 * c];
        p = fmaf(v.x, v.x, p); p = fmaf(v.y, v.y, p);
        p = fmaf(v.z, v.z, p); p = fmaf(v.w, v.w, p);
        ushort4 h, l;
        h.x = f2bf(v.x); l.x = f2bf(v.x - bf2f(h.x));
        h.y = f2bf(v.y); l.y = f2bf(v.y - bf2f(h.y));
        h.z = f2bf(v.z); l.z = f2bf(v.z - bf2f(h.z));
        h.w = f2bf(v.w); l.w = f2bf(v.w - bf2f(h.w));
        const int e = 4 * (lane + 64 * c);
        *(ushort4*)(Hb + (size_t)i * D + e) = h;
        *(ushort4*)(Lb + (size_t)i * D + e) = l;
    }
#pragma unroll
    for (int off = 32; off; off >>= 1) p += __shfl_xor(p, off);
    if (lane == 0) sq[i] = p;
}

// z via MFMA: G = H*H^T + H*L^T + L*H^T (LL^T dropped, ~1e-4 abs on G).
// Block = 16x16 output tile, 4 waves split K=1024 (256 each), LDS reduce.
// A/B frags: row(col)=lane&15, k=(lane>>4)*8+e -> one 16B load per frag.
__global__ __launch_bounds__(256) void k_gram(const unsigned short* __restrict__ Hb,
                                              const unsigned short* __restrict__ Lb,
                                              const float* __restrict__ sq,
                                              float* __restrict__ z) {
    const int i0 = blockIdx.x * 16, j0 = blockIdx.y * 16;
    const int tid = threadIdx.x;
    const int lane = tid & 63, wv = tid >> 6;
    const size_t arow = (size_t)(i0 + (lane & 15)) * D + wv * 256 + (lane >> 4) * 8;
    const size_t brow = (size_t)(j0 + (lane & 15)) * D + wv * 256 + (lane >> 4) * 8;

    f32x4 acc = {0.f, 0.f, 0.f, 0.f};
#pragma unroll
    for (int s = 0; s < 8; ++s) {
        bf16x8 aH = *(const bf16x8*)(Hb + arow + s * 32);
        bf16x8 aL = *(const bf16x8*)(Lb + arow + s * 32);
        bf16x8 bH = *(const bf16x8*)(Hb + brow + s * 32);
        bf16x8 bL = *(const bf16x8*)(Lb + brow + s * 32);
        acc = __builtin_amdgcn_mfma_f32_16x16x32_bf16(aH, bH, acc, 0, 0, 0);
        acc = __builtin_amdgcn_mfma_f32_16x16x32_bf16(aH, bL, acc, 0, 0, 0);
        acc = __builtin_amdgcn_mfma_f32_16x16x32_bf16(aL, bH, acc, 0, 0, 0);
    }
    __shared__ f32x4 red[4][64];
    red[wv][lane] = acc;
    __syncthreads();
    const int ls = tid & 63, r = tid >> 6;
    float g = red[0][ls][r] + red[1][ls][r] + red[2][ls][r] + red[3][ls][r];
    // C/D layout (verified): col = lane&15, row = (lane>>4)*4 + reg
    const int jj = j0 + (ls & 15);
    const int ii = i0 + ((ls >> 4) << 2) + r;
    if (ii != jj) {
        float sd = fmaxf(sq[ii] + sq[jj] - 2.f * g, 0.f);
        z[ii * NM1 + (jj < ii ? jj : jj - 1)] = sqrtf(sd);
    }
}

// Counting-sort each row by y_abs (in place via LDS); emit packed group info
// per sorted element: lo(9b) | hi(9b)<<9 | dense_rank(6b)<<18.
__global__ __launch_bounds__(64) void k_prep(const int* __restrict__ labels,
                                             float* __restrict__ z,
                                             unsigned* __restrict__ gr) {
    const int i = blockIdx.x, tid = threadIdx.x;
    __shared__ float zbuf[NM1];
    __shared__ unsigned char yrow[NM1];
    __shared__ int cnt[64], startv[64], cur[64], rnk[64];
    cnt[tid] = 0;
    for (int k = tid; k < NM1; k += 64) zbuf[k] = z[i * NM1 + k];
    __syncthreads();
    const int li = labels[(i < BSZ) ? i : (i - BSZ)];
    for (int k = tid; k < NM1; k += 64) {
        int col = k + (k >= i ? 1 : 0);
        int ya  = abs(li - labels[(col < BSZ) ? col : (col - BSZ)]);
        yrow[k] = (unsigned char)ya;
        atomicAdd(&cnt[ya], 1);
    }
    __syncthreads();
    if (tid == 0) {
        int c = 0, r = 0;
        for (int v = 0; v < 64; ++v) {
            startv[v] = c;
            rnk[v] = r;
            if (cnt[v] > 0) ++r;
            c += cnt[v];
        }
    }
    __syncthreads();
    cur[tid] = startv[tid];
    __syncthreads();
    for (int k = tid; k < NM1; k += 64) {
        int ya  = yrow[k];
        int pos = atomicAdd(&cur[ya], 1);
        z[i * NM1 + pos] = zbuf[k];
        gr[i * NM1 + pos] = (unsigned)startv[ya]
                          | ((unsigned)(startv[ya] + cnt[ya]) << 9)
                          | ((unsigned)rnk[ya] << 18);
    }
}

// Main sweep: all-pairs (|zk-zj| - |rk-rj|)^2 + sparse same-y correction.
// NO global atomic: per-block partial to its own slot.
__global__ __launch_bounds__(256) void k_main(const float* __restrict__ z,
                                              const unsigned* __restrict__ gr,
                                              float* __restrict__ partial) {
    const int i = blockIdx.x, jt = blockIdx.y, tid = threadIdx.x;
    __shared__ float2 zr[N];      // sorted (z, rank*DELTA); slot 383 zero
    __shared__ unsigned grs[JT];
    for (int k = tid; k < NM1; k += 256) {
        unsigned g = gr[i * NM1 + k];
        zr[k] = make_float2(z[i * NM1 + k], (float)(g >> 18) * DELTA);
    }
    if (tid == 0) zr[NM1] = make_float2(0.f, 0.f);
    const int j0 = jt * JT;
    const int j1 = (j0 + JT < NM1) ? j0 + JT : NM1;
    if (tid < JT && j0 + tid < j1) grs[tid] = gr[i * NM1 + j0 + tid];
    __syncthreads();

    const int  k0 = tid;
    const bool v1 = (tid + 256 < NM1);
    const int  k1 = v1 ? tid + 256 : NM1;    // NM1 slot is (0,0), masked later
    const float zk0 = zr[k0].x, rk0 = zr[k0].y;
    const float zk1 = zr[k1].x, rk1 = zr[k1].y;

    float s0 = 0.f, s1 = 0.f;
#define PAIRQ(q) do { \
        float t0 = fabsf(zk0 - (q).x) - fabsf(rk0 - (q).y); s0 = fmaf(t0, t0, s0); \
        float t1 = fabsf(zk1 - (q).x) - fabsf(rk1 - (q).y); s1 = fmaf(t1, t1, s1); \
    } while (0)
    int j = j0;
    for (; j + 4 <= j1; j += 4) {
        float2 q0 = zr[j], q1 = zr[j+1], q2 = zr[j+2], q3 = zr[j+3];
        PAIRQ(q0); PAIRQ(q1); PAIRQ(q2); PAIRQ(q3);
    }
    for (; j < j1; ++j) { float2 q = zr[j]; PAIRQ(q); }
#undef PAIRQ
    if (!v1) s1 = 0.f;

    // correction over same-y pairs: 4 threads per j, strided over [lo,hi)
    float cs = 0.f;
    const int jj = j0 + (tid >> 2);
    if (jj < j1) {
        const float    zj = zr[jj].x;
        const unsigned g  = grs[tid >> 2];
        const int lo = g & 0x1FF;
        const int hi = (g >> 9) & 0x1FF;
        for (int k = lo + (tid & 3); k < hi; k += 4) {
            float a  = fabsf(zr[k].x - zj);
            float sg = __builtin_amdgcn_rcpf(1.f + __expf(DELTA - a));
            cs += a * sg - a * a;
        }
    }

    float sum = s0 + s1 + cs;
#pragma unroll
    for (int off = 32; off; off >>= 1) sum += __shfl_xor(sum, off);
    __shared__ float part[4];
    if ((tid & 63) == 0) part[tid >> 6] = sum;
    __syncthreads();
    if (tid == 0) partial[i * JB + jt] = part[0] + part[1] + part[2] + part[3];
}

__global__ __launch_bounds__(256) void k_fin(const float* __restrict__ partial,
                                             float* __restrict__ out) {
    const int tid = threadIdx.x;
    double s = 0.0;
    for (int t = tid; t < N * JB; t += 256) s += (double)partial[t];
#pragma unroll
    for (int off = 32; off; off >>= 1) s += __shfl_xor(s, off);
    __shared__ double dp[4];
    if ((tid & 63) == 0) dp[tid >> 6] = s;
    __syncthreads();
    if (tid == 0) {
        const double M = (double)N * (double)NM1 * (double)NM1;
        out[0] = (float)((dp[0] + dp[1] + dp[2] + dp[3]) / M);
    }
}

extern "C" void kernel_launch(void* const* d_in, const int* in_sizes, int n_in,
                              void* d_out, int out_size, void* d_ws, size_t ws_size,
                              hipStream_t stream) {
    const float* feats  = (const float*)d_in[0];
    const int*   labels = (const int*)d_in[1];
    float*       out    = (float*)d_out;

    // ws layout (~2.1 MB total; gr aliases Hb, which is dead after k_gram):
    char* ws = (char*)d_ws;
    float*          sq      = (float*)ws;                         // 1536 B
    float*          partial = (float*)(ws + 2048);                // 9216 B
    unsigned short* Hb      = (unsigned short*)(ws + 16384);      // 768 KiB
    unsigned short* Lb      = (unsigned short*)(ws + 16384 + 786432);       // 768 KiB
    float*          z       = (float*)(ws + 16384 + 2 * 786432);  // 588 KiB
    unsigned*       gr      = (unsigned*)(ws + 16384);            // alias of Hb

    k_cvt <<<N, 64, 0, stream>>>(feats, Hb, Lb, sq);
    k_gram<<<dim3(N / 16, N / 16), 256, 0, stream>>>(Hb, Lb, sq, z);
    k_prep<<<N, 64, 0, stream>>>(labels, z, gr);
    k_main<<<dim3(N, JB), 256, 0, stream>>>(z, gr, partial);
    k_fin <<<1, 256, 0, stream>>>(partial, out);
}

// Round 5
// 44.656 us; speedup vs baseline: 3.4444x; 1.0189x over previous
//
#include <hip/hip_runtime.h>

#define N     384
#define BSZ   192
#define NM1   383
#define D     1024
#define DELTA 0.1f
#define NT    24   // 16-row tiles per dimension in k_gram

typedef __attribute__((ext_vector_type(8))) short bf16x8;
typedef __attribute__((ext_vector_type(4))) float f32x4;

__device__ __forceinline__ const float* feat_row(const float* feats, int i) {
    // features laid out [192][2][1024]; logical row i of the [384,1024] concat
    int b = (i < BSZ) ? i : (i - BSZ);
    int s = (i < BSZ) ? 0 : 1;
    return feats + (size_t)(b * 2 + s) * D;
}

__device__ __forceinline__ unsigned short f2bf(float x) {  // RNE f32->bf16
    unsigned u = __builtin_bit_cast(unsigned, x);
    u = (u + 0x7FFFu + ((u >> 16) & 1u)) >> 16;
    return (unsigned short)u;
}
__device__ __forceinline__ float bf2f(unsigned short h) {
    unsigned u = ((unsigned)h) << 16;
    return __builtin_bit_cast(float, u);
}

// f32 -> (H, L) bf16 split + |f_i|^2; block 0 also zeroes the finalize counter.
__global__ __launch_bounds__(64) void k_cvt(const float* __restrict__ feats,
                                            unsigned short* __restrict__ Hb,
                                            unsigned short* __restrict__ Lb,
                                            float* __restrict__ sq,
                                            unsigned* __restrict__ counter) {
    const int i = blockIdx.x, lane = threadIdx.x;
    if (i == 0 && lane == 0) *counter = 0u;
    const float4* f4 = (const float4*)feat_row(feats, i);
    float p = 0.f;
#pragma unroll
    for (int c = 0; c < 4; ++c) {
        float4 v = f4[lane + 64 * c];
        p = fmaf(v.x, v.x, p); p = fmaf(v.y, v.y, p);
        p = fmaf(v.z, v.z, p); p = fmaf(v.w, v.w, p);
        ushort4 h, l;
        h.x = f2bf(v.x); l.x = f2bf(v.x - bf2f(h.x));
        h.y = f2bf(v.y); l.y = f2bf(v.y - bf2f(h.y));
        h.z = f2bf(v.z); l.z = f2bf(v.z - bf2f(h.z));
        h.w = f2bf(v.w); l.w = f2bf(v.w - bf2f(h.w));
        const int e = 4 * (lane + 64 * c);
        *(ushort4*)(Hb + (size_t)i * D + e) = h;
        *(ushort4*)(Lb + (size_t)i * D + e) = l;
    }
#pragma unroll
    for (int off = 32; off; off >>= 1) p += __shfl_xor(p, off);
    if (lane == 0) sq[i] = p;
}

// z via MFMA: G = H*H^T + H*L^T + L*H^T (LL^T dropped, ~1e-4 abs on G).
// Upper-triangular 16x16 tiles only (300 blocks); mirror-write both z entries.
// 4 waves split K=1024 (256 each), LDS reduce.
__global__ __launch_bounds__(256) void k_gram(const unsigned short* __restrict__ Hb,
                                              const unsigned short* __restrict__ Lb,
                                              const float* __restrict__ sq,
                                              float* __restrict__ z) {
    int t = blockIdx.x, bi = 0;
    while (t >= NT - bi) { t -= NT - bi; ++bi; }
    const int bj = bi + t;
    const int i0 = bi * 16, j0 = bj * 16;

    const int tid = threadIdx.x;
    const int lane = tid & 63, wv = tid >> 6;
    const size_t arow = (size_t)(i0 + (lane & 15)) * D + wv * 256 + (lane >> 4) * 8;
    const size_t brow = (size_t)(j0 + (lane & 15)) * D + wv * 256 + (lane >> 4) * 8;

    f32x4 acc = {0.f, 0.f, 0.f, 0.f};
#pragma unroll
    for (int s = 0; s < 8; ++s) {
        bf16x8 aH = *(const bf16x8*)(Hb + arow + s * 32);
        bf16x8 aL = *(const bf16x8*)(Lb + arow + s * 32);
        bf16x8 bH = *(const bf16x8*)(Hb + brow + s * 32);
        bf16x8 bL = *(const bf16x8*)(Lb + brow + s * 32);
        acc = __builtin_amdgcn_mfma_f32_16x16x32_bf16(aH, bH, acc, 0, 0, 0);
        acc = __builtin_amdgcn_mfma_f32_16x16x32_bf16(aH, bL, acc, 0, 0, 0);
        acc = __builtin_amdgcn_mfma_f32_16x16x32_bf16(aL, bH, acc, 0, 0, 0);
    }
    __shared__ f32x4 red[4][64];
    red[wv][lane] = acc;
    __syncthreads();
    const int ls = tid & 63, r = tid >> 6;
    float g = red[0][ls][r] + red[1][ls][r] + red[2][ls][r] + red[3][ls][r];
    // C/D layout (verified): col = lane&15, row = (lane>>4)*4 + reg
    const int jj = j0 + (ls & 15);
    const int ii = i0 + ((ls >> 4) << 2) + r;
    if (ii != jj) {
        float sd = fmaxf(sq[ii] + sq[jj] - 2.f * g, 0.f);
        float v  = sqrtf(sd);
        z[ii * NM1 + (jj < ii ? jj : jj - 1)] = v;
        z[jj * NM1 + (ii < jj ? ii : ii - 1)] = v;
    }
}

// One block per row: LDS counting sort by y_abs, all-pairs quadratic term,
// sparse same-y correction, per-row partial; last block reduces -> out.
__global__ __launch_bounds__(256) void k_main(const float* __restrict__ z,
                                              const int* __restrict__ labels,
                                              float* __restrict__ partial,
                                              unsigned* __restrict__ counter,
                                              float* __restrict__ out) {
    const int i = blockIdx.x, tid = threadIdx.x;
    __shared__ float zbuf[NM1];
    __shared__ unsigned char yrow[NM1];
    __shared__ int cnt[64], startv[64], cur[64];
    __shared__ float rankd[64];
    __shared__ float2 zr[N];      // sorted (z, rank*DELTA); slot 383 = pad
    __shared__ unsigned grs[N];   // lo | hi<<9 per sorted slot
    __shared__ int lastFlag;

    if (tid < 64) cnt[tid] = 0;
    for (int k = tid; k < NM1; k += 256) zbuf[k] = z[i * NM1 + k];
    __syncthreads();
    const int li = labels[(i < BSZ) ? i : (i - BSZ)];
    for (int k = tid; k < NM1; k += 256) {
        int col = k + (k >= i ? 1 : 0);
        int ya  = abs(li - labels[(col < BSZ) ? col : (col - BSZ)]);
        yrow[k] = (unsigned char)ya;
        atomicAdd(&cnt[ya], 1);
    }
    __syncthreads();
    if (tid == 0) {
        int c = 0, r = 0;
        for (int v = 0; v < 64; ++v) {
            startv[v] = c;
            rankd[v]  = (float)r * DELTA;
            if (cnt[v] > 0) ++r;
            c += cnt[v];
        }
    }
    __syncthreads();
    if (tid < 64) cur[tid] = startv[tid];
    __syncthreads();
    for (int k = tid; k < NM1; k += 256) {
        int ya  = yrow[k];
        int pos = atomicAdd(&cur[ya], 1);
        zr[pos]  = make_float2(zbuf[k], rankd[ya]);
        grs[pos] = (unsigned)startv[ya] | ((unsigned)(startv[ya] + cnt[ya]) << 9);
    }
    if (tid == 0) zr[NM1] = make_float2(0.f, 0.f);
    __syncthreads();

    // all-pairs term: (|zk-zj| - |rk-rj|)^2, 2 k-slots per thread
    const float zk0 = zr[tid].x, rk0 = zr[tid].y;
    const bool  v1  = (tid + 256 < NM1);
    const int   k1  = v1 ? tid + 256 : NM1;   // pad slot; s1 masked below
    const float zk1 = zr[k1].x, rk1 = zr[k1].y;

    float s0 = 0.f, s1 = 0.f;
#define PAIRQ(q) do { \
        float t0 = fabsf(zk0 - (q).x) - fabsf(rk0 - (q).y); s0 = fmaf(t0, t0, s0); \
        float t1 = fabsf(zk1 - (q).x) - fabsf(rk1 - (q).y); s1 = fmaf(t1, t1, s1); \
    } while (0)
    int j = 0;
    for (; j + 4 <= NM1; j += 4) {
        float2 q0 = zr[j], q1 = zr[j+1], q2 = zr[j+2], q3 = zr[j+3];
        PAIRQ(q0); PAIRQ(q1); PAIRQ(q2); PAIRQ(q3);
    }
    for (; j < NM1; ++j) { float2 q = zr[j]; PAIRQ(q); }
#undef PAIRQ
    if (!v1) s1 = 0.f;

    // correction over same-y pairs: a*sigmoid(a-DELTA) - a^2 over [lo,hi)
    float cs = 0.f;
    for (int jj = tid; jj < NM1; jj += 256) {
        const float    zj = zr[jj].x;
        const unsigned g  = grs[jj];
        const int lo = g & 0x1FF;
        const int hi = (g >> 9) & 0x1FF;
        for (int k = lo; k < hi; ++k) {
            float a = fabsf(zr[k].x - zj);
            cs += a * __builtin_amdgcn_rcpf(1.f + __expf(DELTA - a)) - a * a;
        }
    }

    float sum = s0 + s1 + cs;
#pragma unroll
    for (int off = 32; off; off >>= 1) sum += __shfl_xor(sum, off);
    __shared__ float part[4];
    if ((tid & 63) == 0) part[tid >> 6] = sum;
    __syncthreads();
    if (tid == 0) {
        partial[i] = part[0] + part[1] + part[2] + part[3];
        __threadfence();
        unsigned old = atomicAdd(counter, 1u);
        lastFlag = (old == N - 1);
    }
    __syncthreads();

    if (lastFlag) {
        // atomic reads bypass any stale per-XCD L2 lines
        double s = 0.0;
        for (int t = tid; t < N; t += 256) s += (double)atomicAdd(&partial[t], 0.f);
#pragma unroll
        for (int off = 32; off; off >>= 1) s += __shfl_xor(s, off);
        __shared__ double dp[4];
        if ((tid & 63) == 0) dp[tid >> 6] = s;
        __syncthreads();
        if (tid == 0) {
            const double M = (double)N * (double)NM1 * (double)NM1;
            out[0] = (float)((dp[0] + dp[1] + dp[2] + dp[3]) / M);
        }
    }
}

extern "C" void kernel_launch(void* const* d_in, const int* in_sizes, int n_in,
                              void* d_out, int out_size, void* d_ws, size_t ws_size,
                              hipStream_t stream) {
    const float* feats  = (const float*)d_in[0];
    const int*   labels = (const int*)d_in[1];
    float*       out    = (float*)d_out;

    // ws layout (~2.2 MB total):
    char* ws = (char*)d_ws;
    float*          sq      = (float*)ws;                          // 1536 B
    unsigned*       counter = (unsigned*)(ws + 2048);              // 4 B
    float*          partial = (float*)(ws + 4096);                 // 1536 B
    unsigned short* Hb      = (unsigned short*)(ws + 16384);       // 768 KiB
    unsigned short* Lb      = (unsigned short*)(ws + 16384 + 786432);        // 768 KiB
    float*          z       = (float*)(ws + 16384 + 2 * 786432);   // 588 KiB

    k_cvt <<<N, 64, 0, stream>>>(feats, Hb, Lb, sq, counter);
    k_gram<<<NT * (NT + 1) / 2, 256, 0, stream>>>(Hb, Lb, sq, z);
    k_main<<<N, 256, 0, stream>>>(z, labels, partial, counter, out);
}